// Round 1
// baseline (78.896 us; speedup 1.0000x reference)
//
#include <hip/hip_runtime.h>

#define NB   4
#define KCH  4
#define PPB  4096          // downsampled points per batch (64x64)
#define QT   64            // q per block
#define BLK  256           // threads per block
#define PT   2             // p per thread (p-tile = 512)
#define NPT  8             // p-tiles per batch
#define NBLK 288           // triangle blocks per batch: sum(64-8*pt)

#if __has_builtin(__builtin_amdgcn_exp2f)
#define EXPFN(x) __builtin_amdgcn_exp2f(x)
#define FSCALE 1.2011224087864498f   /* sqrt(log2(e)) */
#else
#define EXPFN(x) __expf(x)
#define FSCALE 1.0f
#endif

// Record layout (SoA over 16384 global points, ws-resident):
//   RA[p] = (x, y, r, g)      float4
//   RB[p] = (b, h, s0, s1)    float4   h = -0.5*|f|^2 (log2 units)
//   RC[p] = (s2, s3)          float2
// feats pre-scaled by FSCALE so exp2 needs no extra multiply.

__global__ __launch_bounds__(256) void crf_prep(const float* __restrict__ images,
                                                const float* __restrict__ segs,
                                                float4* __restrict__ RA,
                                                float4* __restrict__ RB,
                                                float2* __restrict__ RC) {
    int gid = blockIdx.x * BLK + threadIdx.x;   // 0..16383
    int n = gid >> 12;
    int p = gid & (PPB - 1);
    int i = p >> 6;
    int j = p & 63;
    int off = 256 * i + 2 * j;                  // pixel (2i, 2j) in 128x128
    const float* img = images + (size_t)n * 3 * 16384;
    float x = (float)j * (FSCALE / 50.0f);      // SIGMA_XY*SCALE = 50
    float y = (float)i * (FSCALE / 50.0f);
    float r = img[off]         * (FSCALE / 15.0f);   // SIGMA_RGB = 15
    float g = img[16384 + off] * (FSCALE / 15.0f);
    float b = img[32768 + off] * (FSCALE / 15.0f);
    float h = -0.5f * (x * x + y * y + r * r + g * g + b * b);
    const float* sg = segs + (size_t)n * KCH * 16384;
    float s0, s1, s2, s3;
    {
        float2 u0 = *(const float2*)(sg + off);
        float2 u1 = *(const float2*)(sg + off + 128);
        s0 = 0.25f * ((u0.x + u0.y) + (u1.x + u1.y));
        u0 = *(const float2*)(sg + 16384 + off);
        u1 = *(const float2*)(sg + 16384 + off + 128);
        s1 = 0.25f * ((u0.x + u0.y) + (u1.x + u1.y));
        u0 = *(const float2*)(sg + 32768 + off);
        u1 = *(const float2*)(sg + 32768 + off + 128);
        s2 = 0.25f * ((u0.x + u0.y) + (u1.x + u1.y));
        u0 = *(const float2*)(sg + 49152 + off);
        u1 = *(const float2*)(sg + 49152 + off + 128);
        s3 = 0.25f * ((u0.x + u0.y) + (u1.x + u1.y));
    }
    RA[gid] = make_float4(x, y, r, g);
    RB[gid] = make_float4(b, h, s0, s1);
    RC[gid] = make_float2(s2, s3);
}

// Pair kernel: p-records in named registers, q-records via wave-uniform
// (scalarizable) loads. No LDS in the inner loop, no prep barrier.
// grid = (288 triangle blocks, 4 batches).
__global__ __launch_bounds__(256) void crf_pairs(const float4* __restrict__ RA,
                                                 const float4* __restrict__ RB,
                                                 const float2* __restrict__ RC,
                                                 float* __restrict__ out) {
    __shared__ float wsum[BLK / 64];
    int t = threadIdx.x;
    int n = blockIdx.y;

    // Decode triangle block index -> (p-tile pt, q-chunk qc), qc >= 8*pt.
    // cum[pt] = 68*pt - 4*pt^2  (closed form, no table -> no scratch risk)
    int b = blockIdx.x;                  // 0..287
    int pt = 0;
    pt += (b >= 64); pt += (b >= 120); pt += (b >= 168); pt += (b >= 208);
    pt += (b >= 240); pt += (b >= 264); pt += (b >= 280);
    int qc = b - pt * (60 - 4 * pt);     // b - cum[pt] + 8*pt
    int pbase = pt * (BLK * PT);
    int qbase = qc * QT;
    bool mixed = (qc >> 3) == pt;        // q-chunk overlaps the p-tile
    int base = n << 12;

    // p-records: PT=2 per thread, fully coalesced float4/float2 loads.
    float4 a0 = RA[base + pbase + t];
    float4 a1 = RA[base + pbase + t + BLK];
    float4 b0 = RB[base + pbase + t];
    float4 b1 = RB[base + pbase + t + BLK];
    float2 c0 = RC[base + pbase + t];
    float2 c1 = RC[base + pbase + t + BLK];

    // q-records: wave-uniform address -> scalar loads into SGPRs.
    const float4* __restrict__ qA = RA + base + qbase;
    const float4* __restrict__ qB = RB + base + qbase;
    const float2* __restrict__ qC = RC + base + qbase;

    float acc0 = 0.f, acc1 = 0.f;
    float acc_all;

    if (!mixed) {
        // Strictly above the diagonal: every pair counts twice.
#pragma unroll 4
        for (int q = 0; q < QT; ++q) {
            float4 fa = qA[q];
            float4 fb = qB[q];
            float2 fc = qC[q];
            float d0 = b0.y + fb.y;
            d0 = fmaf(a0.x, fa.x, d0);
            d0 = fmaf(a0.y, fa.y, d0);
            d0 = fmaf(a0.z, fa.z, d0);
            d0 = fmaf(a0.w, fa.w, d0);
            d0 = fmaf(b0.x, fb.x, d0);
            float w0 = EXPFN(d0);
            float sd0 = b0.z * fb.z;
            sd0 = fmaf(b0.w, fb.w, sd0);
            sd0 = fmaf(c0.x, fc.x, sd0);
            sd0 = fmaf(c0.y, fc.y, sd0);
            acc0 = fmaf(w0, sd0, acc0);

            float d1 = b1.y + fb.y;
            d1 = fmaf(a1.x, fa.x, d1);
            d1 = fmaf(a1.y, fa.y, d1);
            d1 = fmaf(a1.z, fa.z, d1);
            d1 = fmaf(a1.w, fa.w, d1);
            d1 = fmaf(b1.x, fb.x, d1);
            float w1 = EXPFN(d1);
            float sd1 = b1.z * fb.z;
            sd1 = fmaf(b1.w, fb.w, sd1);
            sd1 = fmaf(c1.x, fc.x, sd1);
            sd1 = fmaf(c1.y, fc.y, sd1);
            acc1 = fmaf(w1, sd1, acc1);
        }
        acc_all = 2.0f * (acc0 + acc1);
    } else {
        // Diagonal-overlap block: weight pairs 2/1/0 for q>p / q==p / q<p.
        int pg0 = pbase + t;
        int pg1 = pbase + t + BLK;
#pragma unroll 4
        for (int q = 0; q < QT; ++q) {
            float4 fa = qA[q];
            float4 fb = qB[q];
            float2 fc = qC[q];
            int qg = qbase + q;

            float d0 = b0.y + fb.y;
            d0 = fmaf(a0.x, fa.x, d0);
            d0 = fmaf(a0.y, fa.y, d0);
            d0 = fmaf(a0.z, fa.z, d0);
            d0 = fmaf(a0.w, fa.w, d0);
            d0 = fmaf(b0.x, fb.x, d0);
            float w0 = EXPFN(d0);
            float sd0 = b0.z * fb.z;
            sd0 = fmaf(b0.w, fb.w, sd0);
            sd0 = fmaf(c0.x, fc.x, sd0);
            sd0 = fmaf(c0.y, fc.y, sd0);
            float f0 = (qg > pg0) ? 2.0f : ((qg == pg0) ? 1.0f : 0.0f);
            acc0 = fmaf(w0, sd0 * f0, acc0);

            float d1 = b1.y + fb.y;
            d1 = fmaf(a1.x, fa.x, d1);
            d1 = fmaf(a1.y, fa.y, d1);
            d1 = fmaf(a1.z, fa.z, d1);
            d1 = fmaf(a1.w, fa.w, d1);
            d1 = fmaf(b1.x, fb.x, d1);
            float w1 = EXPFN(d1);
            float sd1 = b1.z * fb.z;
            sd1 = fmaf(b1.w, fb.w, sd1);
            sd1 = fmaf(c1.x, fc.x, sd1);
            sd1 = fmaf(c1.y, fc.y, sd1);
            float f1 = (qg > pg1) ? 2.0f : ((qg == pg1) ? 1.0f : 0.0f);
            acc1 = fmaf(w1, sd1 * f1, acc1);
        }
        acc_all = acc0 + acc1;
    }

#pragma unroll
    for (int off = 32; off > 0; off >>= 1)
        acc_all += __shfl_down(acc_all, off, 64);
    if ((t & 63) == 0) wsum[t >> 6] = acc_all;
    __syncthreads();
    if (t == 0) {
        float s = (wsum[0] + wsum[1]) + (wsum[2] + wsum[3]);
        // loss = WEIGHT * (-sum / n) = -1e-7/4 * sum
        atomicAdd(out, s * (-2.5e-8f));
    }
}

extern "C" void kernel_launch(void* const* d_in, const int* in_sizes, int n_in,
                              void* d_out, int out_size, void* d_ws, size_t ws_size,
                              hipStream_t stream) {
    const float* images = (const float*)d_in[0];
    const float* segs   = (const float*)d_in[1];
    float* out = (float*)d_out;
    char* ws = (char*)d_ws;
    float4* RA = (float4*)(ws);                 // 16384 * 16 B = 256 KiB
    float4* RB = (float4*)(ws + 262144);        // 256 KiB
    float2* RC = (float2*)(ws + 524288);        // 128 KiB
    (void)in_sizes; (void)n_in; (void)out_size; (void)ws_size;

    (void)hipMemsetAsync(out, 0, sizeof(float), stream);
    crf_prep<<<dim3(64), dim3(256), 0, stream>>>(images, segs, RA, RB, RC);
    crf_pairs<<<dim3(NBLK, NB), dim3(256), 0, stream>>>(RA, RB, RC, out);
}

// Round 2
// 77.783 us; speedup vs baseline: 1.0143x; 1.0143x over previous
//
#include <hip/hip_runtime.h>

#define NB   4
#define KCH  4
#define PPB  4096          // downsampled points per batch (64x64)
#define QT   64            // q per block
#define BLK  256           // threads per block
#define PT   4             // p per thread (p-tile = 1024)
#define NBLK 160           // triangle blocks per batch: 64+48+32+16

#if __has_builtin(__builtin_amdgcn_exp2f)
#define EXPFN(x) __builtin_amdgcn_exp2f(x)
#define FSCALE 1.2011224087864498f   /* sqrt(log2(e)) */
#else
#define EXPFN(x) __expf(x)
#define FSCALE 1.0f
#endif

// Record layout (SoA over 16384 global points, ws-resident):
//   RA[p] = (x, y, r, g)      float4
//   RB[p] = (b, h, s0, s1)    float4   h = -0.5*|f|^2 (log2 units)
//   RC[p] = (s2, s3)          float2
// feats pre-scaled by FSCALE so exp2 needs no extra multiply.

__global__ __launch_bounds__(256) void crf_prep(const float* __restrict__ images,
                                                const float* __restrict__ segs,
                                                float4* __restrict__ RA,
                                                float4* __restrict__ RB,
                                                float2* __restrict__ RC,
                                                float* __restrict__ out) {
    int gid = blockIdx.x * BLK + threadIdx.x;   // 0..16383
    if (gid == 0) out[0] = 0.0f;                // replaces memset dispatch
    int n = gid >> 12;
    int p = gid & (PPB - 1);
    int i = p >> 6;
    int j = p & 63;
    int off = 256 * i + 2 * j;                  // pixel (2i, 2j) in 128x128
    const float* img = images + (size_t)n * 3 * 16384;
    float x = (float)j * (FSCALE / 50.0f);      // SIGMA_XY*SCALE = 50
    float y = (float)i * (FSCALE / 50.0f);
    float r = img[off]         * (FSCALE / 15.0f);   // SIGMA_RGB = 15
    float g = img[16384 + off] * (FSCALE / 15.0f);
    float b = img[32768 + off] * (FSCALE / 15.0f);
    float h = -0.5f * (x * x + y * y + r * r + g * g + b * b);
    const float* sg = segs + (size_t)n * KCH * 16384;
    float s0, s1, s2, s3;
    {
        float2 u0 = *(const float2*)(sg + off);
        float2 u1 = *(const float2*)(sg + off + 128);
        s0 = 0.25f * ((u0.x + u0.y) + (u1.x + u1.y));
        u0 = *(const float2*)(sg + 16384 + off);
        u1 = *(const float2*)(sg + 16384 + off + 128);
        s1 = 0.25f * ((u0.x + u0.y) + (u1.x + u1.y));
        u0 = *(const float2*)(sg + 32768 + off);
        u1 = *(const float2*)(sg + 32768 + off + 128);
        s2 = 0.25f * ((u0.x + u0.y) + (u1.x + u1.y));
        u0 = *(const float2*)(sg + 49152 + off);
        u1 = *(const float2*)(sg + 49152 + off + 128);
        s3 = 0.25f * ((u0.x + u0.y) + (u1.x + u1.y));
    }
    RA[gid] = make_float4(x, y, r, g);
    RB[gid] = make_float4(b, h, s0, s1);
    RC[gid] = make_float2(s2, s3);
}

// Pair kernel: PT=4 p-records in registers (4 independent FMA/exp chains per
// q-iter), q-records staged once in LDS and read with a 1-deep register
// prefetch so ds_read latency is never on the critical path.
// grid = (160 triangle blocks, 4 batches).
__global__ __launch_bounds__(256) void crf_pairs(const float4* __restrict__ RA,
                                                 const float4* __restrict__ RB,
                                                 const float2* __restrict__ RC,
                                                 float* __restrict__ out) {
    __shared__ float4 ldsA[QT + 1];     // +1 pad: prefetch overshoot target
    __shared__ float4 ldsB[QT + 1];
    __shared__ float2 ldsC[QT + 1];
    __shared__ float wsum[BLK / 64];

    int t = threadIdx.x;
    int n = blockIdx.y;

    // Decode triangle block index -> (p-tile pt, q-chunk qc), qc >= 16*pt.
    // counts per pt: 64,48,32,16 ; cum = 8*pt*(9-pt)
    int b = blockIdx.x;                  // 0..159
    int pt = (b >= 64) + (b >= 112) + (b >= 144);
    int qc = b - 8 * pt * (7 - pt);      // b - cum + 16*pt
    int pbase = pt * (BLK * PT);         // pt*1024
    int qbase = qc * QT;
    bool mixed = (qc >> 4) == pt;        // q-chunk overlaps the p-tile
    int base = n << 12;

    // Stage q-records into LDS (one-time, coalesced, divergence-free enough).
    if (t < QT)            ldsA[t]          = RA[base + qbase + t];
    else if (t < 2 * QT)   ldsB[t - QT]     = RB[base + qbase + (t - QT)];
    else if (t < 3 * QT)   ldsC[t - 2 * QT] = RC[base + qbase + (t - 2 * QT)];

    // p-records: PT=4 per thread, fully coalesced vector loads, all indices
    // compile-time after unroll -> registers (no scratch).
    float4 pa[PT], pb[PT];
    float2 pc[PT];
#pragma unroll
    for (int pi = 0; pi < PT; ++pi) {
        int idx = base + pbase + t + pi * BLK;
        pa[pi] = RA[idx];
        pb[pi] = RB[idx];
        pc[pi] = RC[idx];
    }
    __syncthreads();

    float acc[PT] = {0.f, 0.f, 0.f, 0.f};
    float acc_all;

    // Prefetch q=0
    float4 fa = ldsA[0];
    float4 fb = ldsB[0];
    float2 fc = ldsC[0];

    if (!mixed) {
        // Strictly above the diagonal: every pair counts twice.
#pragma unroll 2
        for (int q = 0; q < QT; ++q) {
            float4 na = ldsA[q + 1];     // prefetch next (pad slot at q=63)
            float4 nb = ldsB[q + 1];
            float2 nc = ldsC[q + 1];
#pragma unroll
            for (int pi = 0; pi < PT; ++pi) {
                float d = pb[pi].y + fb.y;
                d = fmaf(pa[pi].x, fa.x, d);
                d = fmaf(pa[pi].y, fa.y, d);
                d = fmaf(pa[pi].z, fa.z, d);
                d = fmaf(pa[pi].w, fa.w, d);
                d = fmaf(pb[pi].x, fb.x, d);
                float w = EXPFN(d);
                float sd = pb[pi].z * fb.z;
                sd = fmaf(pb[pi].w, fb.w, sd);
                sd = fmaf(pc[pi].x, fc.x, sd);
                sd = fmaf(pc[pi].y, fc.y, sd);
                acc[pi] = fmaf(w, sd, acc[pi]);
            }
            fa = na; fb = nb; fc = nc;
        }
        acc_all = 2.0f * ((acc[0] + acc[1]) + (acc[2] + acc[3]));
    } else {
        // Diagonal-overlap block: weight pairs 2/1/0 for q>p / q==p / q<p.
#pragma unroll 2
        for (int q = 0; q < QT; ++q) {
            float4 na = ldsA[q + 1];
            float4 nb = ldsB[q + 1];
            float2 nc = ldsC[q + 1];
            int qg = qbase + q;
#pragma unroll
            for (int pi = 0; pi < PT; ++pi) {
                int pg = pbase + t + pi * BLK;
                float d = pb[pi].y + fb.y;
                d = fmaf(pa[pi].x, fa.x, d);
                d = fmaf(pa[pi].y, fa.y, d);
                d = fmaf(pa[pi].z, fa.z, d);
                d = fmaf(pa[pi].w, fa.w, d);
                d = fmaf(pb[pi].x, fb.x, d);
                float w = EXPFN(d);
                float sd = pb[pi].z * fb.z;
                sd = fmaf(pb[pi].w, fb.w, sd);
                sd = fmaf(pc[pi].x, fc.x, sd);
                sd = fmaf(pc[pi].y, fc.y, sd);
                float f = (qg > pg) ? 2.0f : ((qg == pg) ? 1.0f : 0.0f);
                acc[pi] = fmaf(w, sd * f, acc[pi]);
            }
            fa = na; fb = nb; fc = nc;
        }
        acc_all = (acc[0] + acc[1]) + (acc[2] + acc[3]);
    }

#pragma unroll
    for (int off = 32; off > 0; off >>= 1)
        acc_all += __shfl_down(acc_all, off, 64);
    if ((t & 63) == 0) wsum[t >> 6] = acc_all;
    __syncthreads();
    if (t == 0) {
        float s = (wsum[0] + wsum[1]) + (wsum[2] + wsum[3]);
        // loss = WEIGHT * (-sum / n) = -1e-7/4 * sum
        atomicAdd(out, s * (-2.5e-8f));
    }
}

extern "C" void kernel_launch(void* const* d_in, const int* in_sizes, int n_in,
                              void* d_out, int out_size, void* d_ws, size_t ws_size,
                              hipStream_t stream) {
    const float* images = (const float*)d_in[0];
    const float* segs   = (const float*)d_in[1];
    float* out = (float*)d_out;
    char* ws = (char*)d_ws;
    float4* RA = (float4*)(ws);                 // 16384 * 16 B = 256 KiB
    float4* RB = (float4*)(ws + 262144);        // 256 KiB
    float2* RC = (float2*)(ws + 524288);        // 128 KiB
    (void)in_sizes; (void)n_in; (void)out_size; (void)ws_size;

    crf_prep<<<dim3(64), dim3(256), 0, stream>>>(images, segs, RA, RB, RC, out);
    crf_pairs<<<dim3(NBLK, NB), dim3(256), 0, stream>>>(RA, RB, RC, out);
}